// Round 2
// baseline (1268.526 us; speedup 1.0000x reference)
//
#include <hip/hip_runtime.h>

typedef short s16x8 __attribute__((ext_vector_type(8)));
typedef float f32x16 __attribute__((ext_vector_type(16)));
typedef float f32x4 __attribute__((ext_vector_type(4)));

__device__ __forceinline__ float bf2f(short s) {
  unsigned int u = ((unsigned int)(unsigned short)s) << 16;
  return __builtin_bit_cast(float, u);
}
__device__ __forceinline__ short f2bf(float f) {
  unsigned int u = __builtin_bit_cast(unsigned int, f);
  u += 0x7fffu + ((u >> 16) & 1u);   // RNE
  return (short)(u >> 16);
}

#define GEPS 1e-20f

// ---------------- dtype detector (unchanged, proven) ----------------
__global__ __launch_bounds__(256) void k_detect(const short* __restrict__ cb,
                                                int* __restrict__ flag) {
  __shared__ int cnt[256];
  int c = 0;
#pragma unroll
  for (int i = 0; i < 64; ++i) {
    unsigned short v = (unsigned short)cb[threadIdx.x * 64 + i];
    if (((v >> 7) & 0xFF) >= 0x90) ++c;
  }
  cnt[threadIdx.x] = c;
  __syncthreads();
  for (int s = 128; s; s >>= 1) {
    if (threadIdx.x < (unsigned)s) cnt[threadIdx.x] += cnt[threadIdx.x + s];
    __syncthreads();
  }
  if (threadIdx.x == 0) flag[0] = (cnt[0] > 512) ? 1 : 0;
}

// ---------------- codebook prep (unchanged, proven) ----------------
__device__ __forceinline__ int fragidx(int n, int k) {
  return ((((n >> 5) * 64 + (k >> 4)) * 2 + ((k >> 3) & 1)) << 8) + ((n & 31) << 3) + (k & 7);
}

__global__ __launch_bounds__(256) void k_prep(const void* __restrict__ cb,
                                              short* __restrict__ CBhiX,
                                              short* __restrict__ CBloX,
                                              short* __restrict__ CTX,
                                              const int* __restrict__ flag) {
  const int f32m = *flag;
  const int idx = blockIdx.x * 256 + threadIdx.x;   // 1M elements
  const int v = idx >> 10, d = idx & 1023;
  float val;
  if (f32m) val = ((const float*)cb)[idx];
  else      val = bf2f(((const short*)cb)[idx]);
  short hi = f2bf(val);
  short lo = f2bf(val - bf2f(hi));
  CBhiX[fragidx(v, d)] = hi;
  CBloX[fragidx(v, d)] = lo;
  CTX[fragidx(d, v)]   = hi;
}

// ---------------- fused GVQ v3 ----------------
// 512 thr = 8 waves, M=64 rows/block (grid 512, 1 block/CU, 2 waves/EU,
// 256-VGPR cap -- verified-legal occupancy point from v1).
// Wave w owns rows [0,64) (rt in {0,1} -> 32-row sub-tiles) and cols
// [w*128, w*128+128) (nt in [0,4) -> 32-col sub-tiles). acc[2][4] = 128 VGPR.
// GEMM1: K-tiled BK=64, X hi/lo double-buffered in LDS (reg-staged: issue
// next tile's loads before MFMA, convert+write after). GEMM2: K-tiled over v
// (panels of 128), P panel double-buffered in same LDS pool; P kept
// packed-bf16 in 64 regs between softmax and panel write.
// Codebook global traffic: 6 MB x 512 blocks = 3 GB (v1: 6 GB); nontemporal
// hints on all streaming traffic keep the codebook L2-resident.
__global__ __launch_bounds__(512, 2) void k_gvq(
    const void* __restrict__ Xv,
    const short* __restrict__ CBhiX,
    const short* __restrict__ CBloX,
    const short* __restrict__ CTX,
    const void* __restrict__ Gv,
    void* __restrict__ outv,
    const int* __restrict__ flag) {
  // 32 KB pool.
  // GEMM1: buf b at b*8192 shorts; hi = [64r x 64k] at +0, lo at +4096.
  // GEMM2: buf b at b*8192 shorts; P panel [64r x 128v].
  __shared__ __attribute__((aligned(16))) short AP[16384];
  __shared__ float rmaxL[8][64];
  __shared__ float rsumL[8][64];
  __shared__ float rowMax[64];
  __shared__ float rowInv[64];

  const int f32m = *flag;
  const int tid = threadIdx.x;
  const int l  = tid & 63;
  const int w  = tid >> 6;          // wave = column group, [0,8)
  const int ln = l & 31;
  const int h  = l >> 5;
  const int sw = ln & 7;            // (row & 7) for all A-row reads
  const int r0 = blockIdx.x * 64;

  // staging map: 512 threads <-> 64 rows x 8 chunks (8 elems each)
  const int sr = tid >> 3;
  const int sc = tid & 7;
  const int so = sr * 64 + ((sc ^ (sr & 7)) << 3);

  f32x16 acc[2][4];
#pragma unroll
  for (int rt = 0; rt < 2; ++rt)
#pragma unroll
    for (int nt = 0; nt < 4; ++nt)
#pragma unroll
      for (int i = 0; i < 16; ++i) acc[rt][nt][i] = 0.0f;

  const short* bhb = CBhiX + (w * 4) * 32768 + h * 256 + ln * 8;
  const short* blb = CBloX + (w * 4) * 32768 + h * 256 + ln * 8;
  const int abase = ln * 64;        // rt stride = 32*64 = 2048 shorts

  // ---- GEMM1, K-tiled BK=64, double-buffered ----
  if (f32m) {
    // prologue: stage k-tile 0 into buf 0 (hi+lo)
    {
      const float* xp = (const float*)Xv + (r0 + sr) * 1024 + sc * 8;
      f32x4 a = __builtin_nontemporal_load((const f32x4*)xp);
      f32x4 b = __builtin_nontemporal_load((const f32x4*)(xp + 4));
      s16x8 hi8, lo8;
#pragma unroll
      for (int j = 0; j < 8; ++j) {
        float v = (j < 4) ? a[j] : b[j - 4];
        hi8[j] = f2bf(v);
        lo8[j] = f2bf(v - bf2f(hi8[j]));
      }
      *(s16x8*)&AP[so] = hi8;
      *(s16x8*)&AP[4096 + so] = lo8;
    }
    __syncthreads();
    for (int t = 0; t < 16; ++t) {
      const int buf = t & 1;
      f32x4 xa, xb;
      if (t < 15) {   // issue next tile's loads before compute (T14)
        const float* xp = (const float*)Xv + (r0 + sr) * 1024 + (t + 1) * 64 + sc * 8;
        xa = __builtin_nontemporal_load((const f32x4*)xp);
        xb = __builtin_nontemporal_load((const f32x4*)(xp + 4));
      }
      const short* Ah = &AP[buf * 8192] + abase;
      const short* Al = Ah + 4096;
#pragma unroll
      for (int ks = 0; ks < 4; ++ks) {
        const int ao = ((2 * ks + h) ^ sw) << 3;
        s16x8 ah0 = *(const s16x8*)(Ah + ao);
        s16x8 al0 = *(const s16x8*)(Al + ao);
        s16x8 ah1 = *(const s16x8*)(Ah + 2048 + ao);
        s16x8 al1 = *(const s16x8*)(Al + 2048 + ao);
#pragma unroll
        for (int nt = 0; nt < 4; ++nt) {
          const int bo = nt * 32768 + (t * 4 + ks) * 512;
          s16x8 bh = *(const s16x8*)(bhb + bo);
          s16x8 bl = *(const s16x8*)(blb + bo);
          acc[0][nt] = __builtin_amdgcn_mfma_f32_32x32x16_bf16(ah0, bh, acc[0][nt], 0, 0, 0);
          acc[0][nt] = __builtin_amdgcn_mfma_f32_32x32x16_bf16(al0, bh, acc[0][nt], 0, 0, 0);
          acc[0][nt] = __builtin_amdgcn_mfma_f32_32x32x16_bf16(ah0, bl, acc[0][nt], 0, 0, 0);
          acc[1][nt] = __builtin_amdgcn_mfma_f32_32x32x16_bf16(ah1, bh, acc[1][nt], 0, 0, 0);
          acc[1][nt] = __builtin_amdgcn_mfma_f32_32x32x16_bf16(al1, bh, acc[1][nt], 0, 0, 0);
          acc[1][nt] = __builtin_amdgcn_mfma_f32_32x32x16_bf16(ah1, bl, acc[1][nt], 0, 0, 0);
        }
      }
      if (t < 15) {   // convert + write next tile into the other buffer
        s16x8 hi8, lo8;
#pragma unroll
        for (int j = 0; j < 8; ++j) {
          float v = (j < 4) ? xa[j] : xb[j - 4];
          hi8[j] = f2bf(v);
          lo8[j] = f2bf(v - bf2f(hi8[j]));
        }
        short* d = &AP[(buf ^ 1) * 8192] + so;
        *(s16x8*)d = hi8;
        *(s16x8*)(d + 4096) = lo8;
      }
      __syncthreads();
    }
  } else {
    // bf16 input: Xlo = 0 and CBlo = 0 -> single-MFMA inner loop, hi only
    {
      s16x8 hi8 = __builtin_nontemporal_load(
          (const s16x8*)((const short*)Xv + (r0 + sr) * 1024 + sc * 8));
      *(s16x8*)&AP[so] = hi8;
    }
    __syncthreads();
    for (int t = 0; t < 16; ++t) {
      const int buf = t & 1;
      s16x8 xs;
      if (t < 15) {
        xs = __builtin_nontemporal_load(
            (const s16x8*)((const short*)Xv + (r0 + sr) * 1024 + (t + 1) * 64 + sc * 8));
      }
      const short* Ah = &AP[buf * 8192] + abase;
#pragma unroll
      for (int ks = 0; ks < 4; ++ks) {
        const int ao = ((2 * ks + h) ^ sw) << 3;
        s16x8 ah0 = *(const s16x8*)(Ah + ao);
        s16x8 ah1 = *(const s16x8*)(Ah + 2048 + ao);
#pragma unroll
        for (int nt = 0; nt < 4; ++nt) {
          const int bo = nt * 32768 + (t * 4 + ks) * 512;
          s16x8 bh = *(const s16x8*)(bhb + bo);
          acc[0][nt] = __builtin_amdgcn_mfma_f32_32x32x16_bf16(ah0, bh, acc[0][nt], 0, 0, 0);
          acc[1][nt] = __builtin_amdgcn_mfma_f32_32x32x16_bf16(ah1, bh, acc[1][nt], 0, 0, 0);
        }
      }
      if (t < 15) {
        *(s16x8*)(&AP[(buf ^ 1) * 8192] + so) = xs;
      }
      __syncthreads();
    }
  }

  // ---- gumbel + /T; per-row max. C/D: row=(r&3)+8*(r>>2)+4h, col=ln ----
  float pmax[2][16];
#pragma unroll
  for (int rt = 0; rt < 2; ++rt)
#pragma unroll
    for (int r = 0; r < 16; ++r) pmax[rt][r] = -3.0e38f;

#pragma unroll
  for (int rt = 0; rt < 2; ++rt) {
#pragma unroll
    for (int nt = 0; nt < 4; ++nt) {
      const int c = w * 128 + nt * 32 + ln;
      const int rb = r0 + rt * 32;
      float ur[16];
      if (f32m) {
        const float* gp = (const float*)Gv + rb * 1024 + c;
#pragma unroll
        for (int r = 0; r < 16; ++r) {
          const int rho = (r & 3) + 8 * (r >> 2) + 4 * h;
          ur[r] = __builtin_nontemporal_load(gp + rho * 1024);
        }
      } else {
        const short* gp = (const short*)Gv + rb * 1024 + c;
#pragma unroll
        for (int r = 0; r < 16; ++r) {
          const int rho = (r & 3) + 8 * (r >> 2) + 4 * h;
          ur[r] = bf2f(__builtin_nontemporal_load(gp + rho * 1024));
        }
      }
#pragma unroll
      for (int r = 0; r < 16; ++r) {
        float gvn = -__logf(-__logf(ur[r] + GEPS) + GEPS);
        float y = (acc[rt][nt][r] + gvn) * 2.0f;
        acc[rt][nt][r] = y;
        pmax[rt][r] = fmaxf(pmax[rt][r], y);
      }
    }
  }
#pragma unroll
  for (int off = 16; off; off >>= 1)
#pragma unroll
    for (int rt = 0; rt < 2; ++rt)
#pragma unroll
      for (int r = 0; r < 16; ++r)
        pmax[rt][r] = fmaxf(pmax[rt][r], __shfl_xor(pmax[rt][r], off, 64));
  if (ln == 0) {
#pragma unroll
    for (int rt = 0; rt < 2; ++rt)
#pragma unroll
      for (int r = 0; r < 16; ++r)
        rmaxL[w][rt * 32 + (r & 3) + 8 * (r >> 2) + 4 * h] = pmax[rt][r];
  }
  __syncthreads();
  if (tid < 64) {
    float m = rmaxL[0][tid];
#pragma unroll
    for (int j = 1; j < 8; ++j) m = fmaxf(m, rmaxL[j][tid]);
    rowMax[tid] = m;
  }
  __syncthreads();

  // ---- exp + per-row sum ----
  float rm[2][16];
#pragma unroll
  for (int rt = 0; rt < 2; ++rt)
#pragma unroll
    for (int r = 0; r < 16; ++r)
      rm[rt][r] = rowMax[rt * 32 + (r & 3) + 8 * (r >> 2) + 4 * h];
  float psum[2][16];
#pragma unroll
  for (int rt = 0; rt < 2; ++rt)
#pragma unroll
    for (int r = 0; r < 16; ++r) psum[rt][r] = 0.0f;
#pragma unroll
  for (int rt = 0; rt < 2; ++rt)
#pragma unroll
    for (int nt = 0; nt < 4; ++nt)
#pragma unroll
      for (int r = 0; r < 16; ++r) {
        float e = __expf(acc[rt][nt][r] - rm[rt][r]);
        acc[rt][nt][r] = e;
        psum[rt][r] += e;
      }
#pragma unroll
  for (int off = 16; off; off >>= 1)
#pragma unroll
    for (int rt = 0; rt < 2; ++rt)
#pragma unroll
      for (int r = 0; r < 16; ++r)
        psum[rt][r] += __shfl_xor(psum[rt][r], off, 64);
  if (ln == 0) {
#pragma unroll
    for (int rt = 0; rt < 2; ++rt)
#pragma unroll
      for (int r = 0; r < 16; ++r)
        rsumL[w][rt * 32 + (r & 3) + 8 * (r >> 2) + 4 * h] = psum[rt][r];
  }
  __syncthreads();
  if (tid < 64) {
    float s = rsumL[0][tid];
#pragma unroll
    for (int j = 1; j < 8; ++j) s += rsumL[j][tid];
    rowInv[tid] = 1.0f / s;
  }
  __syncthreads();

  // ---- normalize: store soft_one_hot (nontemporal), pack P bf16 in regs ----
  float* outQf = (float*)outv;
  float* outPf = outQf + 33554432;
  short* outQs = (short*)outv;
  short* outPs = outQs + 33554432;

  float ri[2][16];
#pragma unroll
  for (int rt = 0; rt < 2; ++rt)
#pragma unroll
    for (int r = 0; r < 16; ++r)
      ri[rt][r] = rowInv[rt * 32 + (r & 3) + 8 * (r >> 2) + 4 * h];

  unsigned pk[2][4][8];
#pragma unroll
  for (int rt = 0; rt < 2; ++rt) {
#pragma unroll
    for (int nt = 0; nt < 4; ++nt) {
      const int c = w * 128 + nt * 32 + ln;
#pragma unroll
      for (int r = 0; r < 16; ++r) {
        const int row = r0 + rt * 32 + (r & 3) + 8 * (r >> 2) + 4 * h;
        float p = acc[rt][nt][r] * ri[rt][r];
        short pb = f2bf(p);
        if (f32m) __builtin_nontemporal_store(p,  outPf + row * 1024 + c);
        else      __builtin_nontemporal_store(pb, outPs + row * 1024 + c);
        if (r & 1) pk[rt][nt][r >> 1] |= ((unsigned)(unsigned short)pb) << 16;
        else       pk[rt][nt][r >> 1]  = (unsigned)(unsigned short)pb;
      }
    }
  }

  // ---- GEMM2: Q = P @ CB (B = CTX), K-tiled over v in panels of 128 ----
#pragma unroll
  for (int rt = 0; rt < 2; ++rt)
#pragma unroll
    for (int nt = 0; nt < 4; ++nt)
#pragma unroll
      for (int i = 0; i < 16; ++i) acc[rt][nt][i] = 0.0f;

  // wave w holds P columns [w*128, w*128+128) in pk; it writes the LDS panel
  // for GEMM2 k-tile kt == w.
  auto writeP = [&](int bufsel) {
    short* Pb = &AP[bufsel * 8192];
#pragma unroll
    for (int rt = 0; rt < 2; ++rt)
#pragma unroll
      for (int nt = 0; nt < 4; ++nt) {
        const int cl = nt * 32 + ln;            // local col within panel
        const int g = cl >> 3, cs = cl & 7;
#pragma unroll
        for (int r = 0; r < 16; ++r) {
          const int row = rt * 32 + (r & 3) + 8 * (r >> 2) + 4 * h;
          unsigned v = pk[rt][nt][r >> 1];
          short pb = (short)((r & 1) ? (v >> 16) : (v & 0xffffu));
          Pb[row * 128 + (((g ^ (row & 7)) << 3) | cs)] = pb;
        }
      }
  };

  if (w == 0) writeP(0);
  __syncthreads();

  const short* btb = CTX + (w * 4) * 32768 + h * 256 + ln * 8;
  const int pbase = ln * 128;                   // rt stride = 32*128 = 4096
  for (int kt = 0; kt < 8; ++kt) {
    if (kt < 7 && w == kt + 1) writeP((kt + 1) & 1);   // overlap with MFMA
    const short* Pb = &AP[(kt & 1) * 8192] + pbase;
#pragma unroll
    for (int ks = 0; ks < 8; ++ks) {
      const int ao = ((2 * ks + h) ^ sw) << 3;
      s16x8 a0 = *(const s16x8*)(Pb + ao);
      s16x8 a1 = *(const s16x8*)(Pb + 4096 + ao);
#pragma unroll
      for (int nt = 0; nt < 4; ++nt) {
        s16x8 b = *(const s16x8*)(btb + nt * 32768 + (kt * 8 + ks) * 512);
        acc[0][nt] = __builtin_amdgcn_mfma_f32_32x32x16_bf16(a0, b, acc[0][nt], 0, 0, 0);
        acc[1][nt] = __builtin_amdgcn_mfma_f32_32x32x16_bf16(a1, b, acc[1][nt], 0, 0, 0);
      }
    }
    __syncthreads();
  }

  // ---- store quantized direct from regs (nontemporal) ----
#pragma unroll
  for (int rt = 0; rt < 2; ++rt) {
#pragma unroll
    for (int nt = 0; nt < 4; ++nt) {
      const int c = w * 128 + nt * 32 + ln;
#pragma unroll
      for (int r = 0; r < 16; ++r) {
        const int row = r0 + rt * 32 + (r & 3) + 8 * (r >> 2) + 4 * h;
        float q = acc[rt][nt][r];
        if (f32m) __builtin_nontemporal_store(q,       outQf + row * 1024 + c);
        else      __builtin_nontemporal_store(f2bf(q), outQs + row * 1024 + c);
      }
    }
  }
}

extern "C" void kernel_launch(void* const* d_in, const int* in_sizes, int n_in,
                              void* d_out, int out_size, void* d_ws, size_t ws_size,
                              hipStream_t stream) {
  short* wss   = (short*)d_ws;
  short* CBhiX = wss;                  // 2 MB
  short* CBloX = wss + (1 << 20);      // 2 MB
  short* CTX   = wss + (2 << 20);      // 2 MB
  int*   flag  = (int*)(wss + (3 << 20));

  k_detect<<<1, 256, 0, stream>>>((const short*)d_in[1], flag);
  k_prep<<<4096, 256, 0, stream>>>(d_in[1], CBhiX, CBloX, CTX, flag);
  k_gvq<<<512, 512, 0, stream>>>(d_in[0], CBhiX, CBloX, CTX, d_in[2], d_out, flag);
}

// Round 4
// 709.214 us; speedup vs baseline: 1.7886x; 1.7886x over previous
//
#include <hip/hip_runtime.h>

typedef short s16x8 __attribute__((ext_vector_type(8)));
typedef float f32x16 __attribute__((ext_vector_type(16)));
typedef float f32x4 __attribute__((ext_vector_type(4)));

__device__ __forceinline__ float bf2f(short s) {
  unsigned int u = ((unsigned int)(unsigned short)s) << 16;
  return __builtin_bit_cast(float, u);
}
__device__ __forceinline__ short f2bf(float f) {
  unsigned int u = __builtin_bit_cast(unsigned int, f);
  u += 0x7fffu + ((u >> 16) & 1u);   // RNE
  return (short)(u >> 16);
}

#define GEPS 1e-20f

// ---------------- dtype detector (unchanged, proven) ----------------
__global__ __launch_bounds__(256) void k_detect(const short* __restrict__ cb,
                                                int* __restrict__ flag) {
  __shared__ int cnt[256];
  int c = 0;
#pragma unroll
  for (int i = 0; i < 64; ++i) {
    unsigned short v = (unsigned short)cb[threadIdx.x * 64 + i];
    if (((v >> 7) & 0xFF) >= 0x90) ++c;
  }
  cnt[threadIdx.x] = c;
  __syncthreads();
  for (int s = 128; s; s >>= 1) {
    if (threadIdx.x < (unsigned)s) cnt[threadIdx.x] += cnt[threadIdx.x + s];
    __syncthreads();
  }
  if (threadIdx.x == 0) flag[0] = (cnt[0] > 512) ? 1 : 0;
}

// ---------------- codebook prep (unchanged, proven) ----------------
__device__ __forceinline__ int fragidx(int n, int k) {
  return ((((n >> 5) * 64 + (k >> 4)) * 2 + ((k >> 3) & 1)) << 8) + ((n & 31) << 3) + (k & 7);
}

__global__ __launch_bounds__(256) void k_prep(const void* __restrict__ cb,
                                              short* __restrict__ CBhiX,
                                              short* __restrict__ CBloX,
                                              short* __restrict__ CTX,
                                              const int* __restrict__ flag) {
  const int f32m = *flag;
  const int idx = blockIdx.x * 256 + threadIdx.x;   // 1M elements
  const int v = idx >> 10, d = idx & 1023;
  float val;
  if (f32m) val = ((const float*)cb)[idx];
  else      val = bf2f(((const short*)cb)[idx]);
  short hi = f2bf(val);
  short lo = f2bf(val - bf2f(hi));
  CBhiX[fragidx(v, d)] = hi;
  CBloX[fragidx(v, d)] = lo;
  CTX[fragidx(d, v)]   = hi;
}

// ---------------- fused GVQ v4 ----------------
// 512 thr = 8 waves, M=64 rows/block (grid 512). Wave w owns rows [0,64)
// (rt sub-tiles of 32) x cols [w*128,(w+1)*128) (nt sub-tiles of 32).
// v4 changes vs v3 (which spilled: WRITE_SIZE showed +390MB scratch):
//  * full P (64x1024 bf16 = 128 KB) lives in LDS as 8 panels; each wave
//    writes its own panel during normalize -> no pk regs, no writeP lambda,
//    no spills.
//  * GEMM2 is barrier-free (single barrier after P written), A from LDS
//    panels, B streamed from L2 -> compiler can pipeline.
//  * GEMM1 staging overlays panels 0/1 (dead until normalize).
__global__ __launch_bounds__(512, 2) void k_gvq(
    const void* __restrict__ Xv,
    const short* __restrict__ CBhiX,
    const short* __restrict__ CBloX,
    const short* __restrict__ CTX,
    const void* __restrict__ Gv,
    void* __restrict__ outv,
    const int* __restrict__ flag) {
  // 128 KB: P panels [8][64][128] shorts (panel w at w*8192).
  // GEMM1 overlays panels 0/1: buf b at b*8192 (hi at +0, lo at +4096).
  __shared__ __attribute__((aligned(16))) short AP[65536];
  __shared__ float rmaxL[8][64];
  __shared__ float rsumL[8][64];
  __shared__ float rowMax[64];
  __shared__ float rowInv[64];

  const int f32m = *flag;
  const int tid = threadIdx.x;
  const int l  = tid & 63;
  const int w  = tid >> 6;          // wave = column group, [0,8)
  const int ln = l & 31;
  const int h  = l >> 5;
  const int sw = ln & 7;            // (row & 7) for all A-row reads
  const int r0 = blockIdx.x * 64;

  // staging map: 512 threads <-> 64 rows x 8 chunks (8 elems each)
  const int sr = tid >> 3;
  const int sc = tid & 7;
  const int so = sr * 64 + ((sc ^ (sr & 7)) << 3);

  f32x16 acc[2][4];
#pragma unroll
  for (int rt = 0; rt < 2; ++rt)
#pragma unroll
    for (int nt = 0; nt < 4; ++nt)
#pragma unroll
      for (int i = 0; i < 16; ++i) acc[rt][nt][i] = 0.0f;

  const short* bhb = CBhiX + (w * 4) * 32768 + h * 256 + ln * 8;
  const short* blb = CBloX + (w * 4) * 32768 + h * 256 + ln * 8;
  const int abase = ln * 64;        // rt stride = 32*64 = 2048 shorts

  // ---- GEMM1, K-tiled BK=64, double-buffered ----
  if (f32m) {
    {
      const float* xp = (const float*)Xv + (r0 + sr) * 1024 + sc * 8;
      f32x4 a = __builtin_nontemporal_load((const f32x4*)xp);
      f32x4 b = __builtin_nontemporal_load((const f32x4*)(xp + 4));
      s16x8 hi8, lo8;
#pragma unroll
      for (int j = 0; j < 8; ++j) {
        float v = (j < 4) ? a[j] : b[j - 4];
        hi8[j] = f2bf(v);
        lo8[j] = f2bf(v - bf2f(hi8[j]));
      }
      *(s16x8*)&AP[so] = hi8;
      *(s16x8*)&AP[4096 + so] = lo8;
    }
    __syncthreads();
    for (int t = 0; t < 16; ++t) {
      const int buf = t & 1;
      f32x4 xa, xb;
      if (t < 15) {   // issue next tile's loads before compute (T14)
        const float* xp = (const float*)Xv + (r0 + sr) * 1024 + (t + 1) * 64 + sc * 8;
        xa = __builtin_nontemporal_load((const f32x4*)xp);
        xb = __builtin_nontemporal_load((const f32x4*)(xp + 4));
      }
      const short* Ah = &AP[buf * 8192] + abase;
      const short* Al = Ah + 4096;
#pragma unroll
      for (int ks = 0; ks < 4; ++ks) {
        const int ao = ((2 * ks + h) ^ sw) << 3;
        s16x8 ah0 = *(const s16x8*)(Ah + ao);
        s16x8 al0 = *(const s16x8*)(Al + ao);
        s16x8 ah1 = *(const s16x8*)(Ah + 2048 + ao);
        s16x8 al1 = *(const s16x8*)(Al + 2048 + ao);
#pragma unroll
        for (int nt = 0; nt < 4; ++nt) {
          const int bo = nt * 32768 + (t * 4 + ks) * 512;
          s16x8 bh = *(const s16x8*)(bhb + bo);
          s16x8 bl = *(const s16x8*)(blb + bo);
          acc[0][nt] = __builtin_amdgcn_mfma_f32_32x32x16_bf16(ah0, bh, acc[0][nt], 0, 0, 0);
          acc[0][nt] = __builtin_amdgcn_mfma_f32_32x32x16_bf16(al0, bh, acc[0][nt], 0, 0, 0);
          acc[0][nt] = __builtin_amdgcn_mfma_f32_32x32x16_bf16(ah0, bl, acc[0][nt], 0, 0, 0);
          acc[1][nt] = __builtin_amdgcn_mfma_f32_32x32x16_bf16(ah1, bh, acc[1][nt], 0, 0, 0);
          acc[1][nt] = __builtin_amdgcn_mfma_f32_32x32x16_bf16(al1, bh, acc[1][nt], 0, 0, 0);
          acc[1][nt] = __builtin_amdgcn_mfma_f32_32x32x16_bf16(ah1, bl, acc[1][nt], 0, 0, 0);
        }
      }
      if (t < 15) {
        s16x8 hi8, lo8;
#pragma unroll
        for (int j = 0; j < 8; ++j) {
          float v = (j < 4) ? xa[j] : xb[j - 4];
          hi8[j] = f2bf(v);
          lo8[j] = f2bf(v - bf2f(hi8[j]));
        }
        short* d = &AP[(buf ^ 1) * 8192] + so;
        *(s16x8*)d = hi8;
        *(s16x8*)(d + 4096) = lo8;
      }
      __syncthreads();
    }
  } else {
    // bf16 input: Xlo = 0 and CBlo = 0 -> single-MFMA inner loop, hi only
    {
      s16x8 hi8 = __builtin_nontemporal_load(
          (const s16x8*)((const short*)Xv + (r0 + sr) * 1024 + sc * 8));
      *(s16x8*)&AP[so] = hi8;
    }
    __syncthreads();
    for (int t = 0; t < 16; ++t) {
      const int buf = t & 1;
      s16x8 xs;
      if (t < 15) {
        xs = __builtin_nontemporal_load(
            (const s16x8*)((const short*)Xv + (r0 + sr) * 1024 + (t + 1) * 64 + sc * 8));
      }
      const short* Ah = &AP[buf * 8192] + abase;
#pragma unroll
      for (int ks = 0; ks < 4; ++ks) {
        const int ao = ((2 * ks + h) ^ sw) << 3;
        s16x8 ah0 = *(const s16x8*)(Ah + ao);
        s16x8 ah1 = *(const s16x8*)(Ah + 2048 + ao);
#pragma unroll
        for (int nt = 0; nt < 4; ++nt) {
          const int bo = nt * 32768 + (t * 4 + ks) * 512;
          s16x8 bh = *(const s16x8*)(bhb + bo);
          acc[0][nt] = __builtin_amdgcn_mfma_f32_32x32x16_bf16(ah0, bh, acc[0][nt], 0, 0, 0);
          acc[1][nt] = __builtin_amdgcn_mfma_f32_32x32x16_bf16(ah1, bh, acc[1][nt], 0, 0, 0);
        }
      }
      if (t < 15) {
        *(s16x8*)(&AP[(buf ^ 1) * 8192] + so) = xs;
      }
      __syncthreads();
    }
  }

  // ---- gumbel + /T; per-row max. C/D: row=(r&3)+8*(r>>2)+4h, col=ln ----
  float pmax[2][16];
#pragma unroll
  for (int rt = 0; rt < 2; ++rt)
#pragma unroll
    for (int r = 0; r < 16; ++r) pmax[rt][r] = -3.0e38f;

#pragma unroll
  for (int rt = 0; rt < 2; ++rt) {
#pragma unroll
    for (int nt = 0; nt < 4; ++nt) {
      const int c = w * 128 + nt * 32 + ln;
      const int rb = r0 + rt * 32;
      float ur[16];
      if (f32m) {
        const float* gp = (const float*)Gv + rb * 1024 + c;
#pragma unroll
        for (int r = 0; r < 16; ++r) {
          const int rho = (r & 3) + 8 * (r >> 2) + 4 * h;
          ur[r] = __builtin_nontemporal_load(gp + rho * 1024);
        }
      } else {
        const short* gp = (const short*)Gv + rb * 1024 + c;
#pragma unroll
        for (int r = 0; r < 16; ++r) {
          const int rho = (r & 3) + 8 * (r >> 2) + 4 * h;
          ur[r] = bf2f(__builtin_nontemporal_load(gp + rho * 1024));
        }
      }
#pragma unroll
      for (int r = 0; r < 16; ++r) {
        float gvn = -__logf(-__logf(ur[r] + GEPS) + GEPS);
        float y = (acc[rt][nt][r] + gvn) * 2.0f;
        acc[rt][nt][r] = y;
        pmax[rt][r] = fmaxf(pmax[rt][r], y);
      }
    }
  }
#pragma unroll
  for (int off = 16; off; off >>= 1)
#pragma unroll
    for (int rt = 0; rt < 2; ++rt)
#pragma unroll
      for (int r = 0; r < 16; ++r)
        pmax[rt][r] = fmaxf(pmax[rt][r], __shfl_xor(pmax[rt][r], off, 64));
  if (ln == 0) {
#pragma unroll
    for (int rt = 0; rt < 2; ++rt)
#pragma unroll
      for (int r = 0; r < 16; ++r)
        rmaxL[w][rt * 32 + (r & 3) + 8 * (r >> 2) + 4 * h] = pmax[rt][r];
  }
  __syncthreads();
  if (tid < 64) {
    float m = rmaxL[0][tid];
#pragma unroll
    for (int j = 1; j < 8; ++j) m = fmaxf(m, rmaxL[j][tid]);
    rowMax[tid] = m;
  }
  __syncthreads();

  // ---- exp + per-row sum ----
  float rm[2][16];
#pragma unroll
  for (int rt = 0; rt < 2; ++rt)
#pragma unroll
    for (int r = 0; r < 16; ++r)
      rm[rt][r] = rowMax[rt * 32 + (r & 3) + 8 * (r >> 2) + 4 * h];
  float psum[2][16];
#pragma unroll
  for (int rt = 0; rt < 2; ++rt)
#pragma unroll
    for (int r = 0; r < 16; ++r) psum[rt][r] = 0.0f;
#pragma unroll
  for (int rt = 0; rt < 2; ++rt)
#pragma unroll
    for (int nt = 0; nt < 4; ++nt)
#pragma unroll
      for (int r = 0; r < 16; ++r) {
        float e = __expf(acc[rt][nt][r] - rm[rt][r]);
        acc[rt][nt][r] = e;
        psum[rt][r] += e;
      }
#pragma unroll
  for (int off = 16; off; off >>= 1)
#pragma unroll
    for (int rt = 0; rt < 2; ++rt)
#pragma unroll
      for (int r = 0; r < 16; ++r)
        psum[rt][r] += __shfl_xor(psum[rt][r], off, 64);
  if (ln == 0) {
#pragma unroll
    for (int rt = 0; rt < 2; ++rt)
#pragma unroll
      for (int r = 0; r < 16; ++r)
        rsumL[w][rt * 32 + (r & 3) + 8 * (r >> 2) + 4 * h] = psum[rt][r];
  }
  __syncthreads();
  if (tid < 64) {
    float s = rsumL[0][tid];
#pragma unroll
    for (int j = 1; j < 8; ++j) s += rsumL[j][tid];
    rowInv[tid] = 1.0f / s;
  }
  __syncthreads();

  // ---- normalize: store soft_one_hot (nt), write P panel w into LDS ----
  float* outQf = (float*)outv;
  float* outPf = outQf + 33554432;
  short* outQs = (short*)outv;
  short* outPs = outQs + 33554432;

  float ri[2][16];
#pragma unroll
  for (int rt = 0; rt < 2; ++rt)
#pragma unroll
    for (int r = 0; r < 16; ++r)
      ri[rt][r] = rowInv[rt * 32 + (r & 3) + 8 * (r >> 2) + 4 * h];

  {
    short* Pb = &AP[w * 8192];   // panel w: P[:, w*128..w*128+128) [64][128] swizzled
#pragma unroll
    for (int rt = 0; rt < 2; ++rt) {
#pragma unroll
      for (int nt = 0; nt < 4; ++nt) {
        const int c = w * 128 + nt * 32 + ln;
        const int cl = nt * 32 + ln;
        const int g = cl >> 3, cs = cl & 7;
#pragma unroll
        for (int r = 0; r < 16; ++r) {
          const int rloc = rt * 32 + (r & 3) + 8 * (r >> 2) + 4 * h;
          const int row = r0 + rloc;
          float p = acc[rt][nt][r] * ri[rt][r];
          short pb = f2bf(p);
          if (f32m) __builtin_nontemporal_store(p,  outPf + row * 1024 + c);
          else      __builtin_nontemporal_store(pb, outPs + row * 1024 + c);
          Pb[rloc * 128 + (((g ^ (rloc & 7)) << 3) | cs)] = pb;
        }
      }
    }
  }
  __syncthreads();   // full P now in LDS

  // ---- GEMM2: Q = P @ CB (B = CTX), barrier-free over 8 panels ----
#pragma unroll
  for (int rt = 0; rt < 2; ++rt)
#pragma unroll
    for (int nt = 0; nt < 4; ++nt)
#pragma unroll
      for (int i = 0; i < 16; ++i) acc[rt][nt][i] = 0.0f;

  const short* btb = CTX + (w * 4) * 32768 + h * 256 + ln * 8;
  const int pbase = ln * 128;                   // rt stride = 32*128 = 4096
  for (int kt = 0; kt < 8; ++kt) {
    const short* Pb = &AP[kt * 8192] + pbase;
#pragma unroll
    for (int ks = 0; ks < 8; ++ks) {
      const int ao = ((2 * ks + h) ^ sw) << 3;
      s16x8 a0 = *(const s16x8*)(Pb + ao);
      s16x8 a1 = *(const s16x8*)(Pb + 4096 + ao);
#pragma unroll
      for (int nt = 0; nt < 4; ++nt) {
        s16x8 b = *(const s16x8*)(btb + nt * 32768 + (kt * 8 + ks) * 512);
        acc[0][nt] = __builtin_amdgcn_mfma_f32_32x32x16_bf16(a0, b, acc[0][nt], 0, 0, 0);
        acc[1][nt] = __builtin_amdgcn_mfma_f32_32x32x16_bf16(a1, b, acc[1][nt], 0, 0, 0);
      }
    }
  }

  // ---- store quantized direct from regs (nontemporal) ----
#pragma unroll
  for (int rt = 0; rt < 2; ++rt) {
#pragma unroll
    for (int nt = 0; nt < 4; ++nt) {
      const int c = w * 128 + nt * 32 + ln;
#pragma unroll
      for (int r = 0; r < 16; ++r) {
        const int row = r0 + rt * 32 + (r & 3) + 8 * (r >> 2) + 4 * h;
        float q = acc[rt][nt][r];
        if (f32m) __builtin_nontemporal_store(q,       outQf + row * 1024 + c);
        else      __builtin_nontemporal_store(f2bf(q), outQs + row * 1024 + c);
      }
    }
  }
}

extern "C" void kernel_launch(void* const* d_in, const int* in_sizes, int n_in,
                              void* d_out, int out_size, void* d_ws, size_t ws_size,
                              hipStream_t stream) {
  short* wss   = (short*)d_ws;
  short* CBhiX = wss;                  // 2 MB
  short* CBloX = wss + (1 << 20);      // 2 MB
  short* CTX   = wss + (2 << 20);      // 2 MB
  int*   flag  = (int*)(wss + (3 << 20));

  k_detect<<<1, 256, 0, stream>>>((const short*)d_in[1], flag);
  k_prep<<<4096, 256, 0, stream>>>(d_in[1], CBhiX, CBloX, CTX, flag);
  k_gvq<<<512, 512, 0, stream>>>(d_in[0], CBhiX, CBloX, CTX, d_in[2], d_out, flag);
}

// Round 6
// 673.518 us; speedup vs baseline: 1.8834x; 1.0530x over previous
//
#include <hip/hip_runtime.h>

typedef short s16x4 __attribute__((ext_vector_type(4)));
typedef short s16x8 __attribute__((ext_vector_type(8)));
typedef float f32x16 __attribute__((ext_vector_type(16)));
typedef float f32x4 __attribute__((ext_vector_type(4)));

__device__ __forceinline__ float bf2f(short s) {
  unsigned int u = ((unsigned int)(unsigned short)s) << 16;
  return __builtin_bit_cast(float, u);
}
__device__ __forceinline__ short f2bf(float f) {
  unsigned int u = __builtin_bit_cast(unsigned int, f);
  u += 0x7fffu + ((u >> 16) & 1u);   // RNE
  return (short)(u >> 16);
}

#define GEPS 1e-20f

// ---------------- dtype detector (unchanged, proven) ----------------
__global__ __launch_bounds__(256) void k_detect(const short* __restrict__ cb,
                                                int* __restrict__ flag) {
  __shared__ int cnt[256];
  int c = 0;
#pragma unroll
  for (int i = 0; i < 64; ++i) {
    unsigned short v = (unsigned short)cb[threadIdx.x * 64 + i];
    if (((v >> 7) & 0xFF) >= 0x90) ++c;
  }
  cnt[threadIdx.x] = c;
  __syncthreads();
  for (int s = 128; s; s >>= 1) {
    if (threadIdx.x < (unsigned)s) cnt[threadIdx.x] += cnt[threadIdx.x + s];
    __syncthreads();
  }
  if (threadIdx.x == 0) flag[0] = (cnt[0] > 512) ? 1 : 0;
}

// ---------------- codebook prep (unchanged, proven) ----------------
__device__ __forceinline__ int fragidx(int n, int k) {
  return ((((n >> 5) * 64 + (k >> 4)) * 2 + ((k >> 3) & 1)) << 8) + ((n & 31) << 3) + (k & 7);
}

__global__ __launch_bounds__(256) void k_prep(const void* __restrict__ cb,
                                              short* __restrict__ CBhiX,
                                              short* __restrict__ CBloX,
                                              short* __restrict__ CTX,
                                              const int* __restrict__ flag) {
  const int f32m = *flag;
  const int idx = blockIdx.x * 256 + threadIdx.x;   // 1M elements
  const int v = idx >> 10, d = idx & 1023;
  float val;
  if (f32m) val = ((const float*)cb)[idx];
  else      val = bf2f(((const short*)cb)[idx]);
  short hi = f2bf(val);
  short lo = f2bf(val - bf2f(hi));
  CBhiX[fragidx(v, d)] = hi;
  CBloX[fragidx(v, d)] = lo;
  CTX[fragidx(d, v)]   = hi;
}

// ---------------- fused GVQ v5 ----------------
// 1024 thr = 16 waves, M=64 rows/block (grid 512). Wave w owns rows [0,64)
// (rt sub-tiles of 32) x cols [w*64,(w+1)*64) (nt in {0,1}).
// v5 vs v4: same numerics/MFMA order/LDS swizzle, but 16 half-width waves
// instead of 8 full-width. acc = 64 regs/wave -> fits the 128-reg cap of
// __launch_bounds__(1024,4) -> 4 waves/SIMD (v4: 256 regs/wave -> 2/SIMD,
// occupancy-pinned at 23%). rt-sequential softmax keeps live set <=~120.
__global__ __launch_bounds__(1024, 4) void k_gvq(
    const void* __restrict__ Xv,
    const short* __restrict__ CBhiX,
    const short* __restrict__ CBloX,
    const short* __restrict__ CTX,
    const void* __restrict__ Gv,
    void* __restrict__ outv,
    const int* __restrict__ flag) {
  // 128 KB: P panels [16][64][64] shorts (panel w at w*4096).
  // GEMM1 staging overlays panels 0..3: buf b at b*8192 (hi +0, lo +4096).
  __shared__ __attribute__((aligned(16))) short AP[65536];
  __shared__ float rmaxL[16][64];
  __shared__ float rsumL[16][64];
  __shared__ float rowMax[64];
  __shared__ float rowInv[64];

  const int f32m = *flag;
  const int tid = threadIdx.x;
  const int l  = tid & 63;
  const int w  = tid >> 6;          // wave = 64-col group, [0,16)
  const int ln = l & 31;
  const int h  = l >> 5;
  const int sw = ln & 7;            // (row & 7) for all A-row reads
  const int r0 = blockIdx.x * 64;

  // staging map: 1024 threads <-> 64 rows x 16 quarter-chunks (4 elems)
  const int sr = tid >> 4;
  const int scq = tid & 15;
  const int so4 = sr * 64 + ((((scq >> 1) ^ (sr & 7))) << 3) + ((scq & 1) << 2);

  f32x16 acc[2][2];
#pragma unroll
  for (int rt = 0; rt < 2; ++rt)
#pragma unroll
    for (int nt = 0; nt < 2; ++nt)
#pragma unroll
      for (int i = 0; i < 16; ++i) acc[rt][nt][i] = 0.0f;

  const short* bhb = CBhiX + (w * 2) * 32768 + h * 256 + ln * 8;
  const short* blb = CBloX + (w * 2) * 32768 + h * 256 + ln * 8;
  const int abase = ln * 64;        // rt stride = 32*64 = 2048 shorts

  // ---- GEMM1, K-tiled BK=64, double-buffered ----
  if (f32m) {
    {
      const float* xp = (const float*)Xv + (r0 + sr) * 1024 + scq * 4;
      f32x4 a = __builtin_nontemporal_load((const f32x4*)xp);
      s16x4 hi4, lo4;
#pragma unroll
      for (int j = 0; j < 4; ++j) {
        hi4[j] = f2bf(a[j]);
        lo4[j] = f2bf(a[j] - bf2f(hi4[j]));
      }
      *(s16x4*)&AP[so4] = hi4;
      *(s16x4*)&AP[4096 + so4] = lo4;
    }
    __syncthreads();
    for (int t = 0; t < 16; ++t) {
      const int buf = t & 1;
      f32x4 xa;
      if (t < 15) {   // issue next tile's loads before compute (T14)
        const float* xp = (const float*)Xv + (r0 + sr) * 1024 + (t + 1) * 64 + scq * 4;
        xa = __builtin_nontemporal_load((const f32x4*)xp);
      }
      const short* Ah = &AP[buf * 8192] + abase;
      const short* Al = Ah + 4096;
#pragma unroll
      for (int ks = 0; ks < 4; ++ks) {
        const int ao = ((2 * ks + h) ^ sw) << 3;
        s16x8 ah0 = *(const s16x8*)(Ah + ao);
        s16x8 al0 = *(const s16x8*)(Al + ao);
        s16x8 ah1 = *(const s16x8*)(Ah + 2048 + ao);
        s16x8 al1 = *(const s16x8*)(Al + 2048 + ao);
#pragma unroll
        for (int nt = 0; nt < 2; ++nt) {
          const int bo = nt * 32768 + (t * 4 + ks) * 512;
          s16x8 bh = *(const s16x8*)(bhb + bo);
          s16x8 bl = *(const s16x8*)(blb + bo);
          acc[0][nt] = __builtin_amdgcn_mfma_f32_32x32x16_bf16(ah0, bh, acc[0][nt], 0, 0, 0);
          acc[0][nt] = __builtin_amdgcn_mfma_f32_32x32x16_bf16(al0, bh, acc[0][nt], 0, 0, 0);
          acc[0][nt] = __builtin_amdgcn_mfma_f32_32x32x16_bf16(ah0, bl, acc[0][nt], 0, 0, 0);
          acc[1][nt] = __builtin_amdgcn_mfma_f32_32x32x16_bf16(ah1, bh, acc[1][nt], 0, 0, 0);
          acc[1][nt] = __builtin_amdgcn_mfma_f32_32x32x16_bf16(al1, bh, acc[1][nt], 0, 0, 0);
          acc[1][nt] = __builtin_amdgcn_mfma_f32_32x32x16_bf16(ah1, bl, acc[1][nt], 0, 0, 0);
        }
      }
      if (t < 15) {
        s16x4 hi4, lo4;
#pragma unroll
        for (int j = 0; j < 4; ++j) {
          hi4[j] = f2bf(xa[j]);
          lo4[j] = f2bf(xa[j] - bf2f(hi4[j]));
        }
        short* d = &AP[(buf ^ 1) * 8192] + so4;
        *(s16x4*)d = hi4;
        *(s16x4*)(d + 4096) = lo4;
      }
      __syncthreads();
    }
  } else {
    // bf16 input: Xlo = 0 and CBlo = 0 -> single-MFMA inner loop, hi only
    {
      s16x4 hi4 = __builtin_nontemporal_load(
          (const s16x4*)((const short*)Xv + (r0 + sr) * 1024 + scq * 4));
      *(s16x4*)&AP[so4] = hi4;
    }
    __syncthreads();
    for (int t = 0; t < 16; ++t) {
      const int buf = t & 1;
      s16x4 xs;
      if (t < 15) {
        xs = __builtin_nontemporal_load(
            (const s16x4*)((const short*)Xv + (r0 + sr) * 1024 + (t + 1) * 64 + scq * 4));
      }
      const short* Ah = &AP[buf * 8192] + abase;
#pragma unroll
      for (int ks = 0; ks < 4; ++ks) {
        const int ao = ((2 * ks + h) ^ sw) << 3;
        s16x8 ah0 = *(const s16x8*)(Ah + ao);
        s16x8 ah1 = *(const s16x8*)(Ah + 2048 + ao);
#pragma unroll
        for (int nt = 0; nt < 2; ++nt) {
          const int bo = nt * 32768 + (t * 4 + ks) * 512;
          s16x8 bh = *(const s16x8*)(bhb + bo);
          acc[0][nt] = __builtin_amdgcn_mfma_f32_32x32x16_bf16(ah0, bh, acc[0][nt], 0, 0, 0);
          acc[1][nt] = __builtin_amdgcn_mfma_f32_32x32x16_bf16(ah1, bh, acc[1][nt], 0, 0, 0);
        }
      }
      if (t < 15) {
        *(s16x4*)(&AP[(buf ^ 1) * 8192] + so4) = xs;
      }
      __syncthreads();
    }
  }

  // ---- gumbel + /T; per-row max (rt-sequential to cap live regs) ----
  // C/D: row=(r&3)+8*(r>>2)+4h, col=ln
#pragma unroll
  for (int rt = 0; rt < 2; ++rt) {
    float pmax[16];
#pragma unroll
    for (int r = 0; r < 16; ++r) pmax[r] = -3.0e38f;
#pragma unroll
    for (int nt = 0; nt < 2; ++nt) {
      const int c = w * 64 + nt * 32 + ln;
      const int rb = r0 + rt * 32;
      float ur[16];
      if (f32m) {
        const float* gp = (const float*)Gv + rb * 1024 + c;
#pragma unroll
        for (int r = 0; r < 16; ++r) {
          const int rho = (r & 3) + 8 * (r >> 2) + 4 * h;
          ur[r] = __builtin_nontemporal_load(gp + rho * 1024);
        }
      } else {
        const short* gp = (const short*)Gv + rb * 1024 + c;
#pragma unroll
        for (int r = 0; r < 16; ++r) {
          const int rho = (r & 3) + 8 * (r >> 2) + 4 * h;
          ur[r] = bf2f(__builtin_nontemporal_load(gp + rho * 1024));
        }
      }
#pragma unroll
      for (int r = 0; r < 16; ++r) {
        float gvn = -__logf(-__logf(ur[r] + GEPS) + GEPS);
        float y = (acc[rt][nt][r] + gvn) * 2.0f;
        acc[rt][nt][r] = y;
        pmax[r] = fmaxf(pmax[r], y);
      }
    }
#pragma unroll
    for (int off = 16; off; off >>= 1)
#pragma unroll
      for (int r = 0; r < 16; ++r)
        pmax[r] = fmaxf(pmax[r], __shfl_xor(pmax[r], off, 64));
    if (ln == 0) {
#pragma unroll
      for (int r = 0; r < 16; ++r)
        rmaxL[w][rt * 32 + (r & 3) + 8 * (r >> 2) + 4 * h] = pmax[r];
    }
  }
  __syncthreads();
  if (tid < 64) {
    float m = rmaxL[0][tid];
#pragma unroll
    for (int j = 1; j < 16; ++j) m = fmaxf(m, rmaxL[j][tid]);
    rowMax[tid] = m;
  }
  __syncthreads();

  // ---- exp + per-row sum (rt-sequential) ----
#pragma unroll
  for (int rt = 0; rt < 2; ++rt) {
    float psum[16];
#pragma unroll
    for (int r = 0; r < 16; ++r) {
      const int rho = rt * 32 + (r & 3) + 8 * (r >> 2) + 4 * h;
      float rm = rowMax[rho];
      float e0 = __expf(acc[rt][0][r] - rm);
      float e1 = __expf(acc[rt][1][r] - rm);
      acc[rt][0][r] = e0;
      acc[rt][1][r] = e1;
      psum[r] = e0 + e1;
    }
#pragma unroll
    for (int off = 16; off; off >>= 1)
#pragma unroll
      for (int r = 0; r < 16; ++r)
        psum[r] += __shfl_xor(psum[r], off, 64);
    if (ln == 0) {
#pragma unroll
      for (int r = 0; r < 16; ++r)
        rsumL[w][rt * 32 + (r & 3) + 8 * (r >> 2) + 4 * h] = psum[r];
    }
  }
  __syncthreads();
  if (tid < 64) {
    float s = rsumL[0][tid];
#pragma unroll
    for (int j = 1; j < 16; ++j) s += rsumL[j][tid];
    rowInv[tid] = 1.0f / s;
  }
  __syncthreads();

  // ---- normalize: store soft_one_hot (nt), write P panel w into LDS ----
  float* outQf = (float*)outv;
  float* outPf = outQf + 33554432;
  short* outQs = (short*)outv;
  short* outPs = outQs + 33554432;

  {
    short* Pb = &AP[w * 4096];   // panel w: P[:, w*64..w*64+64) [64][64] swizzled
#pragma unroll
    for (int rt = 0; rt < 2; ++rt) {
#pragma unroll
      for (int nt = 0; nt < 2; ++nt) {
        const int c = w * 64 + nt * 32 + ln;
        const int cl = nt * 32 + ln;
        const int g = cl >> 3, cs = cl & 7;
#pragma unroll
        for (int r = 0; r < 16; ++r) {
          const int rloc = rt * 32 + (r & 3) + 8 * (r >> 2) + 4 * h;
          const int row = r0 + rloc;
          float p = acc[rt][nt][r] * rowInv[rloc];
          short pb = f2bf(p);
          if (f32m) __builtin_nontemporal_store(p,  outPf + row * 1024 + c);
          else      __builtin_nontemporal_store(pb, outPs + row * 1024 + c);
          Pb[rloc * 64 + (((g ^ (rloc & 7)) << 3) | cs)] = pb;
        }
      }
    }
  }
  __syncthreads();   // full P now in LDS

  // ---- GEMM2: Q = P @ CB (B = CTX), barrier-free over 16 panels ----
#pragma unroll
  for (int rt = 0; rt < 2; ++rt)
#pragma unroll
    for (int nt = 0; nt < 2; ++nt)
#pragma unroll
      for (int i = 0; i < 16; ++i) acc[rt][nt][i] = 0.0f;

  const short* btb = CTX + (w * 2) * 32768 + h * 256 + ln * 8;
  const int pbase = ln * 64;                    // rt stride = 32*64 = 2048
  for (int kt = 0; kt < 16; ++kt) {
    const short* Pb = &AP[kt * 4096] + pbase;
#pragma unroll
    for (int ks = 0; ks < 4; ++ks) {
      const int ao = ((2 * ks + h) ^ sw) << 3;
      s16x8 a0 = *(const s16x8*)(Pb + ao);
      s16x8 a1 = *(const s16x8*)(Pb + 2048 + ao);
#pragma unroll
      for (int nt = 0; nt < 2; ++nt) {
        s16x8 b = *(const s16x8*)(btb + nt * 32768 + (kt * 4 + ks) * 512);
        acc[0][nt] = __builtin_amdgcn_mfma_f32_32x32x16_bf16(a0, b, acc[0][nt], 0, 0, 0);
        acc[1][nt] = __builtin_amdgcn_mfma_f32_32x32x16_bf16(a1, b, acc[1][nt], 0, 0, 0);
      }
    }
  }

  // ---- store quantized direct from regs (nontemporal) ----
#pragma unroll
  for (int rt = 0; rt < 2; ++rt) {
#pragma unroll
    for (int nt = 0; nt < 2; ++nt) {
      const int c = w * 64 + nt * 32 + ln;
#pragma unroll
      for (int r = 0; r < 16; ++r) {
        const int row = r0 + rt * 32 + (r & 3) + 8 * (r >> 2) + 4 * h;
        float q = acc[rt][nt][r];
        if (f32m) __builtin_nontemporal_store(q,       outQf + row * 1024 + c);
        else      __builtin_nontemporal_store(f2bf(q), outQs + row * 1024 + c);
      }
    }
  }
}

extern "C" void kernel_launch(void* const* d_in, const int* in_sizes, int n_in,
                              void* d_out, int out_size, void* d_ws, size_t ws_size,
                              hipStream_t stream) {
  short* wss   = (short*)d_ws;
  short* CBhiX = wss;                  // 2 MB
  short* CBloX = wss + (1 << 20);      // 2 MB
  short* CTX   = wss + (2 << 20);      // 2 MB
  int*   flag  = (int*)(wss + (3 << 20));

  k_detect<<<1, 256, 0, stream>>>((const short*)d_in[1], flag);
  k_prep<<<4096, 256, 0, stream>>>(d_in[1], CBhiX, CBloX, CTX, flag);
  k_gvq<<<512, 1024, 0, stream>>>(d_in[0], CBhiX, CBloX, CTX, d_in[2], d_out, flag);
}